// Round 2
// baseline (16049.944 us; speedup 1.0000x reference)
//
#include <hip/hip_runtime.h>
#include <hip/hip_bf16.h>

#define L_SIZE 80000
#define C_SIZE 120000
#define N_EDGES 480000
#define DIM 128
#define GDIM 512
#define N_ITER 8

// ---------------------------------------------------------------------------
// Tiled fp32 GEMM: C[rows,N] (+)= act(A[rowmap(rows)] @ B[K,N] + bias)
//  - A row r (chunk-local) reads global row (rowBase + r) ^ rowXor, stride lda
//  - C is chunk-local, row-major stride N
//  - accum: C += result (no bias/relu applied in that case unless set)
// Tile 64x64, BK=32, 256 threads, 4x4 per thread. rows%64==0, N%64==0, K%32==0.
// ---------------------------------------------------------------------------
__global__ __launch_bounds__(256) void gemm_kernel(
    const float* __restrict__ A, int lda, int rowBase, int rowXor,
    const float* __restrict__ B, const float* __restrict__ bias,
    float* __restrict__ C, int N, int K, int relu, int accum)
{
    __shared__ float As[64][33];   // +1 pad: kills stride-32 bank conflict on As[row][kk]
    __shared__ float Bs[32][64];
    const int tid = threadIdx.x;
    const int tx = tid & 15, ty = tid >> 4;
    const int bx = blockIdx.x, by = blockIdx.y;

    float acc[4][4] = {};

    for (int k0 = 0; k0 < K; k0 += 32) {
        #pragma unroll
        for (int i = 0; i < 8; ++i) {
            int idx = tid + i * 256;          // 0..2047 over 64x32 A tile
            int r = idx >> 5, c = idx & 31;
            int gr = (rowBase + by * 64 + r) ^ rowXor;
            As[r][c] = A[(size_t)gr * lda + k0 + c];
        }
        #pragma unroll
        for (int i = 0; i < 8; ++i) {
            int idx = tid + i * 256;          // 0..2047 over 32x64 B tile
            int r = idx >> 6, c = idx & 63;
            Bs[r][c] = B[(size_t)(k0 + r) * N + bx * 64 + c];
        }
        __syncthreads();
        #pragma unroll
        for (int kk = 0; kk < 32; ++kk) {
            float a[4], b[4];
            #pragma unroll
            for (int i = 0; i < 4; ++i) a[i] = As[ty * 4 + i][kk];
            #pragma unroll
            for (int j = 0; j < 4; ++j) b[j] = Bs[kk][tx * 4 + j];
            #pragma unroll
            for (int i = 0; i < 4; ++i)
                #pragma unroll
                for (int j = 0; j < 4; ++j)
                    acc[i][j] += a[i] * b[j];
        }
        __syncthreads();
    }

    float bv[4];
    #pragma unroll
    for (int j = 0; j < 4; ++j) bv[j] = bias ? bias[bx * 64 + tx * 4 + j] : 0.f;
    #pragma unroll
    for (int i = 0; i < 4; ++i) {
        size_t row = (size_t)(by * 64 + ty * 4 + i);
        #pragma unroll
        for (int j = 0; j < 4; ++j) {
            float v = acc[i][j] + bv[j];
            if (relu) v = fmaxf(v, 0.f);
            size_t idx = row * N + bx * 64 + tx * 4 + j;
            if (accum) C[idx] += v; else C[idx] = v;
        }
    }
}

// ---------------------------------------------------------------------------
// Edge scatter: aggr[dst[e]][0:128] += msg[src[e]][0:128], one thread/(e,d).
// ---------------------------------------------------------------------------
__global__ __launch_bounds__(256) void scatter_kernel(
    const float* __restrict__ msg, const int* __restrict__ src_idx,
    const int* __restrict__ dst_idx, float* __restrict__ aggr)
{
    size_t idx = (size_t)blockIdx.x * 256 + threadIdx.x;
    if (idx >= (size_t)N_EDGES * DIM) return;
    int e = (int)(idx >> 7);
    int d = (int)(idx & 127);
    int si = src_idx[e], di = dst_idx[e];
    atomicAdd(&aggr[(size_t)di * DIM + d], msg[(size_t)si * DIM + d]);
}

// ---------------------------------------------------------------------------
// LayerNorm-LSTM pointwise epilogue. One 128-thread block per row (chunked).
// Thread d owns gate dims {d, d+128, d+256, d+384} = {i, f, g, o}[d].
// X/H are chunk-local [rows,512]; cprev/c_out/h_out indexed at rowBase+row.
// ---------------------------------------------------------------------------
__global__ __launch_bounds__(128) void lnlstm_kernel(
    const float* __restrict__ X, const float* __restrict__ H, int rowBase,
    const float* __restrict__ cprev,
    const float* __restrict__ g_ih, const float* __restrict__ b_ih,
    const float* __restrict__ g_hh, const float* __restrict__ b_hh,
    const float* __restrict__ g_c, const float* __restrict__ b_c,
    float* __restrict__ c_out, float* __restrict__ h_out)
{
    const int rl = blockIdx.x;                 // chunk-local row
    const size_t rg = (size_t)(rowBase + rl);  // global row
    const int d = threadIdx.x;                 // 0..127
    const int lane = d & 63, wid = d >> 6;
    const float* Xr = X + (size_t)rl * GDIM;
    const float* Hr = H + (size_t)rl * GDIM;

    float x[4], h[4];
    float sx = 0.f, qx = 0.f, sh = 0.f, qh = 0.f;
    #pragma unroll
    for (int k = 0; k < 4; ++k) {
        x[k] = Xr[d + 128 * k];
        h[k] = Hr[d + 128 * k];
        sx += x[k]; qx += x[k] * x[k];
        sh += h[k]; qh += h[k] * h[k];
    }

    __shared__ float red[8];
    #pragma unroll
    for (int off = 32; off; off >>= 1) {
        sx += __shfl_down(sx, off);
        qx += __shfl_down(qx, off);
        sh += __shfl_down(sh, off);
        qh += __shfl_down(qh, off);
    }
    if (lane == 0) {
        red[wid * 4 + 0] = sx; red[wid * 4 + 1] = qx;
        red[wid * 4 + 2] = sh; red[wid * 4 + 3] = qh;
    }
    __syncthreads();
    sx = red[0] + red[4]; qx = red[1] + red[5];
    sh = red[2] + red[6]; qh = red[3] + red[7];

    const float inv512 = 1.f / 512.f;
    float mux = sx * inv512, muh = sh * inv512;
    float vx = qx * inv512 - mux * mux;
    float vh = qh * inv512 - muh * muh;
    float rx = rsqrtf(vx + 1e-5f), rh = rsqrtf(vh + 1e-5f);

    float gate[4];
    #pragma unroll
    for (int k = 0; k < 4; ++k) {
        int j = d + 128 * k;
        gate[k] = (x[k] - mux) * rx * g_ih[j] + b_ih[j]
                + (h[k] - muh) * rh * g_hh[j] + b_hh[j];
    }
    float iv = 1.f / (1.f + expf(-gate[0]));
    float fv = 1.f / (1.f + expf(-gate[1]));
    float gv = tanhf(gate[2]);
    float ov = 1.f / (1.f + expf(-gate[3]));

    float c = fv * cprev[rg * DIM + d] + iv * gv;

    float sc = c, qc = c * c;
    #pragma unroll
    for (int off = 32; off; off >>= 1) {
        sc += __shfl_down(sc, off);
        qc += __shfl_down(qc, off);
    }
    __syncthreads();                     // red[] reuse: wait for phase-1 reads
    if (lane == 0) { red[wid * 2] = sc; red[wid * 2 + 1] = qc; }
    __syncthreads();
    sc = red[0] + red[2]; qc = red[1] + red[3];

    const float inv128 = 1.f / 128.f;
    float muc = sc * inv128;
    float vc = qc * inv128 - muc * muc;
    float rc = rsqrtf(vc + 1e-5f);
    float hn = ov * tanhf((c - muc) * rc * g_c[d] + b_c[d]);

    c_out[rg * DIM + d] = c;
    h_out[rg * DIM + d] = hn;
}

// ---------------------------------------------------------------------------
static inline void gemm_launch(const float* A, int lda, int rowBase, int rowXor,
                               const float* B, const float* bias, float* C,
                               int rows, int N, int K, int relu, int accum,
                               hipStream_t stream)
{
    dim3 grid(N / 64, rows / 64);
    gemm_kernel<<<grid, 256, 0, stream>>>(A, lda, rowBase, rowXor, B, bias, C,
                                          N, K, relu, accum);
}

extern "C" void kernel_launch(void* const* d_in, const int* in_sizes, int n_in,
                              void* d_out, int out_size, void* d_ws, size_t ws_size,
                              hipStream_t stream)
{
    const int*   l_edge  = (const int*)d_in[2];
    const int*   c_edge  = (const int*)d_in[3];
    const float* l_emb0  = (const float*)d_in[4];
    const float* c_emb0  = (const float*)d_in[5];
    const float* l2c_w1  = (const float*)d_in[6];
    const float* l2c_b1  = (const float*)d_in[7];
    const float* l2c_w2  = (const float*)d_in[8];
    const float* l2c_b2  = (const float*)d_in[9];
    const float* c2l_w1  = (const float*)d_in[10];
    const float* c2l_b1  = (const float*)d_in[11];
    const float* c2l_w2  = (const float*)d_in[12];
    const float* c2l_b2  = (const float*)d_in[13];
    const float* cu_wi   = (const float*)d_in[14];
    const float* cu_wh   = (const float*)d_in[15];
    const float* cu_g_ih = (const float*)d_in[16];
    const float* cu_b_ih = (const float*)d_in[17];
    const float* cu_g_hh = (const float*)d_in[18];
    const float* cu_b_hh = (const float*)d_in[19];
    const float* cu_g_c  = (const float*)d_in[20];
    const float* cu_b_c  = (const float*)d_in[21];
    const float* lu_wi   = (const float*)d_in[22];
    const float* lu_wh   = (const float*)d_in[23];
    const float* lu_g_ih = (const float*)d_in[24];
    const float* lu_b_ih = (const float*)d_in[25];
    const float* lu_g_hh = (const float*)d_in[26];
    const float* lu_b_hh = (const float*)d_in[27];
    const float* lu_g_c  = (const float*)d_in[28];
    const float* lu_b_c  = (const float*)d_in[29];

    float* out = (float*)d_out;
    float* l_slab = out;                              // [9, L, 128]
    float* c_slab = out + (size_t)9 * L_SIZE * DIM;   // [9, C, 128]

    // ---- workspace partition (floats), sized to ws_size ----
    float* w = (float*)d_ws;
    float* l_state = w; w += (size_t)L_SIZE * DIM;    // 10.24M
    float* c_state = w; w += (size_t)C_SIZE * DIM;    // 15.36M
    float* msg     = w; w += (size_t)C_SIZE * DIM;    // 15.36M  (MLP output, max(L,C) rows)
    float* aggr    = w; w += (size_t)C_SIZE * DIM;    // 15.36M  (c-aggr / l-aggr, disjoint phases)
    float* regA    = w;                               // rest: hidden OR Xg|Hg (disjoint phases)
    size_t used  = (size_t)(w - (float*)d_ws);
    size_t avail = ws_size / sizeof(float);
    size_t rest  = avail > used ? avail - used : 0;

    // LSTM chunk: needs chunk*1024 floats (Xg+Hg). MLP chunk: chunk_m*128 (hidden).
    int chunk = (int)(rest / 1024); chunk = (chunk / 64) * 64;
    if (chunk < 64) chunk = 64;
    if (chunk > C_SIZE) chunk = C_SIZE;
    int chunk_m = (int)(rest / 128); chunk_m = (chunk_m / 64) * 64;
    if (chunk_m < 64) chunk_m = 64;
    if (chunk_m > C_SIZE) chunk_m = C_SIZE;
    float* Xg = regA;
    float* Hg = regA + (size_t)chunk * GDIM;
    float* hidden = regA;

    // slab 0 = inputs; states start at zero
    hipMemcpyAsync(l_slab, l_emb0, (size_t)L_SIZE * DIM * sizeof(float),
                   hipMemcpyDeviceToDevice, stream);
    hipMemcpyAsync(c_slab, c_emb0, (size_t)C_SIZE * DIM * sizeof(float),
                   hipMemcpyDeviceToDevice, stream);
    hipMemsetAsync(l_state, 0, (size_t)L_SIZE * DIM * sizeof(float), stream);
    hipMemsetAsync(c_state, 0, (size_t)C_SIZE * DIM * sizeof(float), stream);

    const int scatter_blocks = (N_EDGES * DIM) / 256;

    for (int t = 0; t < N_ITER; ++t) {
        const float* le = l_slab + (size_t)t * L_SIZE * DIM;
        const float* ce = c_slab + (size_t)t * C_SIZE * DIM;
        float* le1 = l_slab + (size_t)(t + 1) * L_SIZE * DIM;
        float* ce1 = c_slab + (size_t)(t + 1) * C_SIZE * DIM;

        // ======== literal -> clause ========
        // msg = MLP(le), chunked over rows through `hidden`
        for (int b = 0; b < L_SIZE; b += chunk_m) {
            int rows = L_SIZE - b < chunk_m ? L_SIZE - b : chunk_m;
            gemm_launch(le, DIM, b, 0, l2c_w1, l2c_b1, hidden,
                        rows, DIM, DIM, 1, 0, stream);
            gemm_launch(hidden, DIM, 0, 0, l2c_w2, l2c_b2, msg + (size_t)b * DIM,
                        rows, DIM, DIM, 0, 0, stream);
        }
        hipMemsetAsync(aggr, 0, (size_t)C_SIZE * DIM * sizeof(float), stream);
        scatter_kernel<<<scatter_blocks, 256, 0, stream>>>(msg, l_edge, c_edge, aggr);

        // clause LSTM, chunked
        for (int b = 0; b < C_SIZE; b += chunk) {
            int rows = C_SIZE - b < chunk ? C_SIZE - b : chunk;
            gemm_launch(aggr, DIM, b, 0, cu_wi, nullptr, Xg, rows, GDIM, DIM, 0, 0, stream);
            gemm_launch(ce,   DIM, b, 0, cu_wh, nullptr, Hg, rows, GDIM, DIM, 0, 0, stream);
            lnlstm_kernel<<<rows, 128, 0, stream>>>(Xg, Hg, b, c_state,
                                                    cu_g_ih, cu_b_ih, cu_g_hh, cu_b_hh,
                                                    cu_g_c, cu_b_c, c_state, ce1);
        }

        // ======== clause -> literal ========
        for (int b = 0; b < C_SIZE; b += chunk_m) {
            int rows = C_SIZE - b < chunk_m ? C_SIZE - b : chunk_m;
            gemm_launch(ce1, DIM, b, 0, c2l_w1, c2l_b1, hidden,
                        rows, DIM, DIM, 1, 0, stream);
            gemm_launch(hidden, DIM, 0, 0, c2l_w2, c2l_b2, msg + (size_t)b * DIM,
                        rows, DIM, DIM, 0, 0, stream);
        }
        hipMemsetAsync(aggr, 0, (size_t)L_SIZE * DIM * sizeof(float), stream);
        scatter_kernel<<<scatter_blocks, 256, 0, stream>>>(msg, c_edge, l_edge, aggr);

        // literal LSTM, chunked.
        // X = concat(c2l_aggr, l2l) @ lu_wi = aggr@lu_wi[0:128] + flip(le)@lu_wi[128:256]
        for (int b = 0; b < L_SIZE; b += chunk) {
            int rows = L_SIZE - b < chunk ? L_SIZE - b : chunk;
            gemm_launch(aggr, DIM, b, 0, lu_wi,                  nullptr, Xg,
                        rows, GDIM, DIM, 0, 0, stream);
            gemm_launch(le,   DIM, b, 1, lu_wi + (size_t)DIM * GDIM, nullptr, Xg,
                        rows, GDIM, DIM, 0, 1, stream);
            gemm_launch(le,   DIM, b, 0, lu_wh, nullptr, Hg, rows, GDIM, DIM, 0, 0, stream);
            lnlstm_kernel<<<rows, 128, 0, stream>>>(Xg, Hg, b, l_state,
                                                    lu_g_ih, lu_b_ih, lu_g_hh, lu_b_hh,
                                                    lu_g_c, lu_b_c, l_state, le1);
        }
    }
}